// Round 7
// baseline (169.730 us; speedup 1.0000x reference)
//
#include <hip/hip_runtime.h>

// Problem constants (fixed by setup_inputs): N=2048, B=64, H=W=4096, ks=8
#define GRIDN 64        // block positions per axis (H/B)
#define NCELLS 4096     // GRIDN*GRIDN
#define BVEC 8192       // float4 per block: 64*64*8/4
#define ROWSTRIDE4 8192 // float4 per dense row: W*ks/4

// ws layout (int32 units)
#define WS_CNT 0        // 4096 ints: per-cell block count
#define WS_CID 4096     // 1024 ints: 2048 ushorts, per-block cell id

typedef float f32x4 __attribute__((ext_vector_type(4)));

// ---------------------------------------------------------------------------
// Tiny setup (1 wg): dtype-detect + per-block cellid + per-cell counts.
__global__ __launch_bounds__(1024) void k_setup(const int* __restrict__ idxw,
                                                int N, int* __restrict__ ws_i) {
    __shared__ int counts_s[NCELLS];  // 16 KB
    __shared__ int f64_s;
    const int tid = threadIdx.x;

    // int64 little-endian with values in [0,64): every odd 32-bit word of the
    // first 2N words is a zero high-half. int32: odd words are col indices.
    int local = 0;
    for (int i = 1 + 2 * tid; i < 2 * N; i += 2048) local |= idxw[i];
    if (tid == 0) f64_s = 0;
    for (int i = tid; i < NCELLS; i += 1024) counts_s[i] = 0;
    __syncthreads();
    if (local) f64_s = 1;  // benign race, all write 1
    __syncthreads();
    const int is64 = (f64_s == 0);

    unsigned short* cid = (unsigned short*)(ws_i + WS_CID);
    for (int n = tid; n < N; n += 1024) {
        int r, c;
        if (is64) {
            const long long* p = (const long long*)idxw;
            r = (int)p[2 * n];
            c = (int)p[2 * n + 1];
        } else {
            r = idxw[2 * n];
            c = idxw[2 * n + 1];
        }
        int cell = (r >= 0 && r < GRIDN && c >= 0 && c < GRIDN) ? r * GRIDN + c
                                                                : 0xFFFF;
        cid[n] = (unsigned short)cell;
        if (cell != 0xFFFF) atomicAdd(&counts_s[cell], 1);
    }
    __syncthreads();
    for (int i = tid; i < NCELLS; i += 1024) ws_i[WS_CNT + i] = counts_s[i];
}

// ---------------------------------------------------------------------------
// Dense gather: 16384 wgs = 4096 cells x 4 chunks, 256 threads.
// Empty cells (61%): one scalar count load -> straight to zero stores
// (no scan / LDS / barrier). Non-empty: ballot-scan the 4 KB cellid array,
// ascending-n extraction (deterministic order identical to all prior rounds).
__global__ __launch_bounds__(256) void k_dense(const int* __restrict__ ws_i,
                                               const f32x4* __restrict__ bv4,
                                               f32x4* __restrict__ out4,
                                               int N) {
    const int cell = blockIdx.x >> 2;
    const int chunk = blockIdx.x & 3;
    const int R = cell >> 6;
    const int C = cell & (GRIDN - 1);
    const int tid = threadIdx.x;
    const int tbase = chunk * 2048 + tid;
    const size_t obase = (size_t)(R * 64) * ROWSTRIDE4 + (size_t)C * 128;
    const int cnt = ws_i[WS_CNT + cell];  // wg-uniform scalar load

    if (cnt == 0) {
        const f32x4 z = {0.f, 0.f, 0.f, 0.f};
#pragma unroll
        for (int i = 0; i < 8; ++i) {
            int t = tbase + i * 256;
            __builtin_nontemporal_store(z, &out4[obase + (size_t)(t >> 7) * ROWSTRIDE4 + (t & 127)]);
        }
        return;
    }

    // ---- ballot scan of precomputed cellids (4 KB, L2-resident) ----
    const int w = tid >> 6;
    const int lane = tid & 63;
    __shared__ unsigned long long masks[32];
    __shared__ short list_s[2048];
    __shared__ int cnt_chk;

    const unsigned short* cid = (const unsigned short*)(ws_i + WS_CID);
#pragma unroll
    for (int k = 0; k < 8; ++k) {
        const int n = w * 512 + k * 64 + lane;
        const bool match = (n < N) && ((int)cid[n] == cell);
        unsigned long long mk = __ballot(match);
        if (lane == 0) masks[w * 8 + k] = mk;
    }
    __syncthreads();

    // parallel ordered extraction (wave 0, lanes 0..31)
    if (tid < 64) {
        unsigned long long mk = (lane < 32) ? masks[lane] : 0ULL;
        const int pc = __popcll(mk);
        int pre = pc;  // inclusive prefix over lanes 0..31
#pragma unroll
        for (int d = 1; d < 32; d <<= 1) {
            int v = __shfl_up(pre, d, 64);
            if (lane >= d) pre += v;
        }
        int pos = pre - pc;  // exclusive
        const int base = lane * 64;
        while (mk) {
            const int b = __ffsll(mk) - 1;
            list_s[pos++] = (short)(base + b);
            mk &= mk - 1;
        }
    }
    __syncthreads();

    // ---- streaming (identical structure to rounds 2/4/5/6) ----
    if (cnt == 1) {
        const f32x4* __restrict__ src = bv4 + (size_t)list_s[0] * BVEC;
#pragma unroll
        for (int i = 0; i < 8; ++i) {
            int t = tbase + i * 256;
            f32x4 v = __builtin_nontemporal_load(&src[t]);
            __builtin_nontemporal_store(v, &out4[obase + (size_t)(t >> 7) * ROWSTRIDE4 + (t & 127)]);
        }
    } else {
        f32x4 acc[8];
#pragma unroll
        for (int i = 0; i < 8; ++i) acc[i] = (f32x4){0.f, 0.f, 0.f, 0.f};
        for (int j = 0; j < cnt; ++j) {
            const f32x4* __restrict__ src = bv4 + (size_t)list_s[j] * BVEC;
#pragma unroll
            for (int i = 0; i < 8; ++i)
                acc[i] += __builtin_nontemporal_load(&src[tbase + i * 256]);
        }
#pragma unroll
        for (int i = 0; i < 8; ++i) {
            int t = tbase + i * 256;
            __builtin_nontemporal_store(acc[i], &out4[obase + (size_t)(t >> 7) * ROWSTRIDE4 + (t & 127)]);
        }
    }
}

// ---------------------------------------------------------------------------
extern "C" void kernel_launch(void* const* d_in, const int* in_sizes, int n_in,
                              void* d_out, int out_size, void* d_ws, size_t ws_size,
                              hipStream_t stream) {
    const float* bv = (const float*)d_in[0];
    const int* idxw = (const int*)d_in[1];
    const int N = in_sizes[1] / 2;  // 2048 blocks

    int* ws_i = (int*)d_ws;

    k_setup<<<1, 1024, 0, stream>>>(idxw, N, ws_i);
    k_dense<<<NCELLS * 4, 256, 0, stream>>>(ws_i, (const f32x4*)bv,
                                            (f32x4*)d_out, N);
}